// Round 1
// baseline (345.231 us; speedup 1.0000x reference)
//
#include <hip/hip_runtime.h>
#include <hip/hip_bf16.h>
#include <stdint.h>

#define T_TOK 8192
#define DIM   1024
#define NEXP  16
#define ESZ   256
#define TOPK  4
#define BM    128
#define BK    64
#define MAXROWS (T_TOK*TOPK + NEXP*BM)     // 34816 padded assignment rows
#define MAXTILES (T_TOK*TOPK/BM + NEXP)    // 272

typedef __hip_bfloat16 bf16;
typedef short bf16x8 __attribute__((ext_vector_type(8)));
typedef float f32x4 __attribute__((ext_vector_type(4)));

__device__ __forceinline__ unsigned short f2bu(float f){
  __hip_bfloat16 b = __float2bfloat16(f);
  return *reinterpret_cast<unsigned short*>(&b);
}

__device__ __forceinline__ void gload16(const void* g, void* l){
  __builtin_amdgcn_global_load_lds((const __attribute__((address_space(1))) void*)g,
                                   (__attribute__((address_space(3))) void*)l, 16, 0, 0);
}

// ---------------- gating: logits -> sigmoid -> top4, fused x->bf16 ----------
__global__ __launch_bounds__(256) void k_gate(const float* __restrict__ x,
    const float* __restrict__ wg, bf16* __restrict__ xb,
    int* __restrict__ sel_idx, float* __restrict__ sel_gate)
{
  const int wave = threadIdx.x >> 6, lane = threadIdx.x & 63;
  const int t = blockIdx.x*4 + wave;
  const float* xr = x + (size_t)t*DIM;
  float4 xv[4];
#pragma unroll
  for (int c=0;c<4;c++) xv[c] = *(const float4*)(xr + c*256 + lane*4);
#pragma unroll
  for (int c=0;c<4;c++){
    ushort4 o; o.x=f2bu(xv[c].x); o.y=f2bu(xv[c].y); o.z=f2bu(xv[c].z); o.w=f2bu(xv[c].w);
    *(ushort4*)((unsigned short*)xb + (size_t)t*DIM + c*256 + lane*4) = o;
  }
  float sg[NEXP];
#pragma unroll
  for (int e=0;e<NEXP;e++){
    const float* wr = wg + e*DIM;
    float p = 0.f;
#pragma unroll
    for (int c=0;c<4;c++){
      float4 w = *(const float4*)(wr + c*256 + lane*4);
      p += xv[c].x*w.x + xv[c].y*w.y + xv[c].z*w.z + xv[c].w*w.w;
    }
#pragma unroll
    for (int s=1;s<64;s<<=1) p += __shfl_xor(p, s);
    sg[e] = 1.f/(1.f + expf(-p));
  }
  if (lane==0){
    unsigned chosen = 0;
#pragma unroll
    for (int k=0;k<TOPK;k++){
      float best=-1.f; int bi=0;
#pragma unroll
      for (int e=0;e<NEXP;e++){
        float v = ((chosen>>e)&1u) ? -2.f : sg[e];
        if (v>best){best=v;bi=e;}
      }
      chosen |= 1u<<bi;
      sel_idx[t*TOPK+k]=bi; sel_gate[t*TOPK+k]=best;
    }
  }
}

// ---------------- fp32 [R][C] -> bf16 [C][R] transpose (per expert) ---------
__global__ __launch_bounds__(256) void k_transpose(const float* __restrict__ in,
    bf16* __restrict__ out, int R, int C)
{
  __shared__ float tile[32][33];
  const float* src = in + (size_t)blockIdx.z*R*C;
  bf16* dst = out + (size_t)blockIdx.z*R*C;
  int tx = threadIdx.x & 31, ty = threadIdx.x >> 5;
  int r0 = blockIdx.y*32, c0 = blockIdx.x*32;
#pragma unroll
  for (int i=0;i<4;i++){ int r = ty + i*8; tile[r][tx] = src[(size_t)(r0+r)*C + c0 + tx]; }
  __syncthreads();
#pragma unroll
  for (int i=0;i<4;i++){ int r = ty + i*8; dst[(size_t)(c0+r)*R + r0 + tx] = __float2bfloat16(tile[tx][r]); }
}

// ---------------- histogram + padded offsets + tile map ---------------------
__global__ void k_meta(const int* __restrict__ sel_idx,
    int* __restrict__ cursors, int* __restrict__ tile_expert,
    int* __restrict__ tile_rowstart, int* __restrict__ tile_segend)
{
  __shared__ int cnt[NEXP];
  if (threadIdx.x < NEXP) cnt[threadIdx.x]=0;
  __syncthreads();
  for (int i=threadIdx.x; i<T_TOK*TOPK; i+=blockDim.x) atomicAdd(&cnt[sel_idx[i]],1);
  __syncthreads();
  if (threadIdx.x==0){
    int off=0, tc=0;
    for (int e=0;e<NEXP;e++){
      int c = cnt[e];
      cursors[e] = off;
      int nt = (c + BM - 1)/BM;
      for (int i=0;i<nt;i++){
        tile_expert[tc]=e; tile_rowstart[tc]=off+i*BM; tile_segend[tc]=off+c; tc++;
      }
      off += nt*BM;            // 128-padded segments: tiles never overlap experts
    }
    for (; tc<MAXTILES; tc++) tile_expert[tc]=-1;
  }
}

// ---------------- wave-aggregated scatter of (token, gate) ------------------
__global__ __launch_bounds__(256) void k_scatter(const int* __restrict__ sel_idx,
    const float* __restrict__ sel_gate, int* __restrict__ cursors,
    int* __restrict__ assign_token, float* __restrict__ assign_gate)
{
  const int t = blockIdx.x*blockDim.x + threadIdx.x;
  const int lane = threadIdx.x & 63;
  for (int k=0;k<TOPK;k++){
    int e = sel_idx[t*TOPK+k]; float g = sel_gate[t*TOPK+k];
    for (int ee=0; ee<NEXP; ee++){
      unsigned long long m = __ballot(e==ee);
      if (e==ee){
        int leader = __ffsll((unsigned long long)m)-1;
        int rank = __popcll(m & ((1ull<<lane)-1ull));
        int base = 0;
        if (lane==leader) base = atomicAdd(&cursors[ee], (int)__popcll(m));
        base = __shfl(base, leader);
        assign_token[base+rank]=t; assign_gate[base+rank]=g;
      }
    }
  }
}

// ---------------- GEMM1: h = bf16( relu(Xg @ keys_e) * gate ) ---------------
__global__ __launch_bounds__(256) void k_gemm1(
    const bf16* __restrict__ xb, const bf16* __restrict__ kT,
    const int* __restrict__ assign_token, const float* __restrict__ assign_gate,
    const int* __restrict__ tile_expert, const int* __restrict__ tile_rowstart,
    const int* __restrict__ tile_segend, bf16* __restrict__ h)
{
  __shared__ char smem[BM*BK*2*2];     // A 16KB + B 16KB (bf16)
  __shared__ int   tokens_s[BM];
  __shared__ float gates_s[BM];

  const int tile = blockIdx.x, nb = blockIdx.y;
  const int e = tile_expert[tile];
  if (e < 0) return;
  const int row0 = tile_rowstart[tile];
  const int segend = tile_segend[tile];
  const int tid = threadIdx.x, wave = tid>>6, lane = tid&63;

  if (tid < BM){
    int rg = row0 + tid;
    bool vld = rg < segend;
    tokens_s[tid] = vld ? assign_token[rg] : 0;
    gates_s[tid]  = vld ? assign_gate[rg] : 0.f;
  }
  __syncthreads();

  char* As = smem; char* Bs = smem + BM*BK*2;
  const bf16* gA[4]; const bf16* gB[4]; char* lA[4]; char* lB[4];
#pragma unroll
  for (int i=0;i<4;i++){
    int rl = (wave*4+i)*8 + (lane>>3);
    int c  = (lane&7) ^ (rl&7);                 // source-side XOR pre-swizzle
    gA[i] = xb + (size_t)tokens_s[rl]*DIM + c*8;
    lA[i] = As + (wave*4+i)*1024;
    gB[i] = kT + ((size_t)e*ESZ + nb*BM + rl)*DIM + c*8;
    lB[i] = Bs + (wave*4+i)*1024;
  }

  f32x4 acc[4][4];
#pragma unroll
  for (int m=0;m<4;m++)
#pragma unroll
    for (int n=0;n<4;n++) acc[m][n] = {0.f,0.f,0.f,0.f};

  const int wr0 = (wave>>1)*64, wc0 = (wave&1)*64;

  for (int kt=0; kt<DIM/BK; ++kt){
#pragma unroll
    for (int i=0;i<4;i++){ gload16(gA[i] + kt*BK, lA[i]); gload16(gB[i] + kt*BK, lB[i]); }
    asm volatile("s_waitcnt vmcnt(0)" ::: "memory");
    __syncthreads();
#pragma unroll
    for (int kk=0;kk<2;kk++){
      bf16x8 af[4], bfr[4];
#pragma unroll
      for (int m=0;m<4;m++){
        int row = wr0 + m*16 + (lane&15);
        int kb  = kk*64 + (lane>>4)*16;
        af[m] = *(const bf16x8*)(As + row*128 + (kb ^ ((row&7)<<4)));
      }
#pragma unroll
      for (int n=0;n<4;n++){
        int col = wc0 + n*16 + (lane&15);
        int kb  = kk*64 + (lane>>4)*16;
        bfr[n] = *(const bf16x8*)(Bs + col*128 + (kb ^ ((col&7)<<4)));
      }
#pragma unroll
      for (int m=0;m<4;m++)
#pragma unroll
        for (int n=0;n<4;n++)
          acc[m][n] = __builtin_amdgcn_mfma_f32_16x16x32_bf16(af[m], bfr[n], acc[m][n], 0,0,0);
    }
    __syncthreads();
  }

#pragma unroll
  for (int m=0;m<4;m++)
#pragma unroll
    for (int n=0;n<4;n++){
      int col = wc0 + n*16 + (lane&15);
#pragma unroll
      for (int j=0;j<4;j++){
        int rloc = wr0 + m*16 + ((lane>>4)<<2) + j;
        float v = fmaxf(acc[m][n][j], 0.f) * gates_s[rloc];
        h[(size_t)(row0 + rloc)*ESZ + nb*BM + col] = __float2bfloat16(v);
      }
    }
}

// ---------------- GEMM2: out[token] += h_rows @ values_e --------------------
__global__ __launch_bounds__(256) void k_gemm2(
    const bf16* __restrict__ h, const bf16* __restrict__ vT,
    const int* __restrict__ assign_token,
    const int* __restrict__ tile_expert, const int* __restrict__ tile_rowstart,
    const int* __restrict__ tile_segend, float* __restrict__ out)
{
  __shared__ char smem[BM*BK*2*2];
  __shared__ int tokens_s[BM];

  const int tile = blockIdx.x, nb = blockIdx.y;
  const int e = tile_expert[tile];
  if (e < 0) return;
  const int row0 = tile_rowstart[tile];
  const int segend = tile_segend[tile];
  const int tid = threadIdx.x, wave = tid>>6, lane = tid&63;

  if (tid < BM){
    int rg = row0 + tid;
    tokens_s[tid] = (rg < segend) ? assign_token[rg] : 0;
  }
  __syncthreads();

  char* As = smem; char* Bs = smem + BM*BK*2;
  const bf16* gA[4]; const bf16* gB[4]; char* lA[4]; char* lB[4];
#pragma unroll
  for (int i=0;i<4;i++){
    int rl = (wave*4+i)*8 + (lane>>3);
    int c  = (lane&7) ^ (rl&7);
    gA[i] = h + (size_t)(row0 + rl)*ESZ + c*8;
    lA[i] = As + (wave*4+i)*1024;
    gB[i] = vT + ((size_t)e*DIM + nb*BM + rl)*ESZ + c*8;
    lB[i] = Bs + (wave*4+i)*1024;
  }

  f32x4 acc[4][4];
#pragma unroll
  for (int m=0;m<4;m++)
#pragma unroll
    for (int n=0;n<4;n++) acc[m][n] = {0.f,0.f,0.f,0.f};

  const int wr0 = (wave>>1)*64, wc0 = (wave&1)*64;

  for (int kt=0; kt<ESZ/BK; ++kt){
#pragma unroll
    for (int i=0;i<4;i++){ gload16(gA[i] + kt*BK, lA[i]); gload16(gB[i] + kt*BK, lB[i]); }
    asm volatile("s_waitcnt vmcnt(0)" ::: "memory");
    __syncthreads();
#pragma unroll
    for (int kk=0;kk<2;kk++){
      bf16x8 af[4], bfr[4];
#pragma unroll
      for (int m=0;m<4;m++){
        int row = wr0 + m*16 + (lane&15);
        int kb  = kk*64 + (lane>>4)*16;
        af[m] = *(const bf16x8*)(As + row*128 + (kb ^ ((row&7)<<4)));
      }
#pragma unroll
      for (int n=0;n<4;n++){
        int col = wc0 + n*16 + (lane&15);
        int kb  = kk*64 + (lane>>4)*16;
        bfr[n] = *(const bf16x8*)(Bs + col*128 + (kb ^ ((col&7)<<4)));
      }
#pragma unroll
      for (int m=0;m<4;m++)
#pragma unroll
        for (int n=0;n<4;n++)
          acc[m][n] = __builtin_amdgcn_mfma_f32_16x16x32_bf16(af[m], bfr[n], acc[m][n], 0,0,0);
    }
    __syncthreads();
  }

#pragma unroll
  for (int m=0;m<4;m++)
#pragma unroll
    for (int n=0;n<4;n++){
      int col = wc0 + n*16 + (lane&15);
#pragma unroll
      for (int j=0;j<4;j++){
        int rloc = wr0 + m*16 + ((lane>>4)<<2) + j;
        if (row0 + rloc < segend)
          atomicAdd(out + (size_t)tokens_s[rloc]*DIM + nb*BM + col, acc[m][n][j]);
      }
    }
}

// ---------------------------------------------------------------------------
extern "C" void kernel_launch(void* const* d_in, const int* in_sizes, int n_in,
                              void* d_out, int out_size, void* d_ws, size_t ws_size,
                              hipStream_t stream)
{
  const float* x      = (const float*)d_in[0];
  const float* wg     = (const float*)d_in[1];
  const float* keys   = (const float*)d_in[2];
  const float* values = (const float*)d_in[3];
  float* out = (float*)d_out;

  char* ws = (char*)d_ws;
  size_t off = 0;
  bf16* xb   = (bf16*)(ws+off); off += (size_t)T_TOK*DIM*2;      // 16 MB
  bf16* kT   = (bf16*)(ws+off); off += (size_t)NEXP*ESZ*DIM*2;   // 8 MB
  bf16* vT   = (bf16*)(ws+off); off += (size_t)NEXP*DIM*ESZ*2;   // 8 MB
  bf16* hbuf = (bf16*)(ws+off); off += (size_t)MAXROWS*ESZ*2;    // 17 MB
  int*   sel_idx      = (int*)  (ws+off); off += (size_t)T_TOK*TOPK*4;
  float* sel_gate     = (float*)(ws+off); off += (size_t)T_TOK*TOPK*4;
  int*   assign_token = (int*)  (ws+off); off += (size_t)MAXROWS*4;
  float* assign_gate  = (float*)(ws+off); off += (size_t)MAXROWS*4;
  int*   cursors      = (int*)  (ws+off); off += 256;
  int*   tile_expert  = (int*)  (ws+off); off += 4096;
  int*   tile_rowstart= (int*)  (ws+off); off += 4096;
  int*   tile_segend  = (int*)  (ws+off); off += 4096;

  hipMemsetAsync(d_out, 0, (size_t)out_size*sizeof(float), stream);

  k_gate<<<T_TOK/4, 256, 0, stream>>>(x, wg, xb, sel_idx, sel_gate);
  k_transpose<<<dim3(ESZ/32, DIM/32, NEXP), 256, 0, stream>>>(keys, kT, DIM, ESZ);
  k_transpose<<<dim3(DIM/32, ESZ/32, NEXP), 256, 0, stream>>>(values, vT, ESZ, DIM);
  k_meta<<<1, 256, 0, stream>>>(sel_idx, cursors, tile_expert, tile_rowstart, tile_segend);
  k_scatter<<<T_TOK/256, 256, 0, stream>>>(sel_idx, sel_gate, cursors, assign_token, assign_gate);
  k_gemm1<<<dim3(MAXTILES, ESZ/BM), 256, 0, stream>>>(xb, kT, assign_token, assign_gate,
      tile_expert, tile_rowstart, tile_segend, hbuf);
  k_gemm2<<<dim3(MAXTILES, DIM/BM), 256, 0, stream>>>(hbuf, vT, assign_token,
      tile_expert, tile_rowstart, tile_segend, out);
}

// Round 2
// 278.834 us; speedup vs baseline: 1.2381x; 1.2381x over previous
//
#include <hip/hip_runtime.h>
#include <hip/hip_bf16.h>
#include <stdint.h>

#define T_TOK 8192
#define DIM   1024
#define NEXP  16
#define ESZ   256
#define TOPK  4
#define BM    128
#define BK    64
#define MAXROWS (T_TOK*TOPK + NEXP*BM)     // 34816 padded assignment rows
#define MAXTILES (T_TOK*TOPK/BM + NEXP)    // 272

typedef __hip_bfloat16 bf16;
typedef short bf16x8 __attribute__((ext_vector_type(8)));
typedef float f32x4 __attribute__((ext_vector_type(4)));

__device__ __forceinline__ unsigned short f2bu(float f){
  __hip_bfloat16 b = __float2bfloat16(f);
  return *reinterpret_cast<unsigned short*>(&b);
}
__device__ __forceinline__ float bu2f(unsigned short u){
  __hip_bfloat16 b = *reinterpret_cast<__hip_bfloat16*>(&u);
  return __bfloat162float(b);
}

__device__ __forceinline__ void gload16(const void* g, void* l){
  __builtin_amdgcn_global_load_lds((const __attribute__((address_space(1))) void*)g,
                                   (__attribute__((address_space(3))) void*)l, 16, 0, 0);
}

// ---------------- gating: logits -> sigmoid -> top4, fused x->bf16 ----------
__global__ __launch_bounds__(256) void k_gate(const float* __restrict__ x,
    const float* __restrict__ wg, bf16* __restrict__ xb,
    int* __restrict__ sel_idx, float* __restrict__ sel_gate)
{
  const int wave = threadIdx.x >> 6, lane = threadIdx.x & 63;
  const int t = blockIdx.x*4 + wave;
  const float* xr = x + (size_t)t*DIM;
  float4 xv[4];
#pragma unroll
  for (int c=0;c<4;c++) xv[c] = *(const float4*)(xr + c*256 + lane*4);
#pragma unroll
  for (int c=0;c<4;c++){
    ushort4 o; o.x=f2bu(xv[c].x); o.y=f2bu(xv[c].y); o.z=f2bu(xv[c].z); o.w=f2bu(xv[c].w);
    *(ushort4*)((unsigned short*)xb + (size_t)t*DIM + c*256 + lane*4) = o;
  }
  float sg[NEXP];
#pragma unroll
  for (int e=0;e<NEXP;e++){
    const float* wr = wg + e*DIM;
    float p = 0.f;
#pragma unroll
    for (int c=0;c<4;c++){
      float4 w = *(const float4*)(wr + c*256 + lane*4);
      p += xv[c].x*w.x + xv[c].y*w.y + xv[c].z*w.z + xv[c].w*w.w;
    }
#pragma unroll
    for (int s=1;s<64;s<<=1) p += __shfl_xor(p, s);
    sg[e] = 1.f/(1.f + expf(-p));
  }
  if (lane==0){
    unsigned chosen = 0;
#pragma unroll
    for (int k=0;k<TOPK;k++){
      float best=-1.f; int bi=0;
#pragma unroll
      for (int e=0;e<NEXP;e++){
        float v = ((chosen>>e)&1u) ? -2.f : sg[e];
        if (v>best){best=v;bi=e;}
      }
      chosen |= 1u<<bi;
      sel_idx[t*TOPK+k]=bi; sel_gate[t*TOPK+k]=best;
    }
  }
}

// ---------------- fp32 [R][C] -> bf16 [C][R] transpose (per expert) ---------
__global__ __launch_bounds__(256) void k_transpose(const float* __restrict__ in,
    bf16* __restrict__ out, int R, int C)
{
  __shared__ float tile[32][33];
  const float* src = in + (size_t)blockIdx.z*R*C;
  bf16* dst = out + (size_t)blockIdx.z*R*C;
  int tx = threadIdx.x & 31, ty = threadIdx.x >> 5;
  int r0 = blockIdx.y*32, c0 = blockIdx.x*32;
#pragma unroll
  for (int i=0;i<4;i++){ int r = ty + i*8; tile[r][tx] = src[(size_t)(r0+r)*C + c0 + tx]; }
  __syncthreads();
#pragma unroll
  for (int i=0;i<4;i++){ int r = ty + i*8; dst[(size_t)(c0+r)*R + r0 + tx] = __float2bfloat16(tile[tx][r]); }
}

// ---------------- histogram + padded offsets + tile map ---------------------
__global__ void k_meta(const int* __restrict__ sel_idx,
    int* __restrict__ cursors, int* __restrict__ tile_expert,
    int* __restrict__ tile_rowstart, int* __restrict__ tile_segend)
{
  __shared__ int cnt[NEXP];
  if (threadIdx.x < NEXP) cnt[threadIdx.x]=0;
  __syncthreads();
  for (int i=threadIdx.x; i<T_TOK*TOPK; i+=blockDim.x) atomicAdd(&cnt[sel_idx[i]],1);
  __syncthreads();
  if (threadIdx.x==0){
    int off=0, tc=0;
    for (int e=0;e<NEXP;e++){
      int c = cnt[e];
      cursors[e] = off;
      int nt = (c + BM - 1)/BM;
      for (int i=0;i<nt;i++){
        tile_expert[tc]=e; tile_rowstart[tc]=off+i*BM; tile_segend[tc]=off+c; tc++;
      }
      off += nt*BM;            // 128-padded segments: tiles never overlap experts
    }
    for (; tc<MAXTILES; tc++) tile_expert[tc]=-1;
  }
}

// -------- wave-aggregated scatter of (token, gate) + inverse map ------------
__global__ __launch_bounds__(256) void k_scatter(const int* __restrict__ sel_idx,
    const float* __restrict__ sel_gate, int* __restrict__ cursors,
    int* __restrict__ assign_token, float* __restrict__ assign_gate,
    int* __restrict__ inv_rows)
{
  const int t = blockIdx.x*blockDim.x + threadIdx.x;
  const int lane = threadIdx.x & 63;
  for (int k=0;k<TOPK;k++){
    int e = sel_idx[t*TOPK+k]; float g = sel_gate[t*TOPK+k];
    for (int ee=0; ee<NEXP; ee++){
      unsigned long long m = __ballot(e==ee);
      if (e==ee){
        int leader = __ffsll((unsigned long long)m)-1;
        int rank = __popcll(m & ((1ull<<lane)-1ull));
        int base = 0;
        if (lane==leader) base = atomicAdd(&cursors[ee], (int)__popcll(m));
        base = __shfl(base, leader);
        int row = base+rank;
        assign_token[row]=t; assign_gate[row]=g;
        inv_rows[t*TOPK+k]=row;
      }
    }
  }
}

// ---------------- GEMM1: h = bf16( relu(Xg @ keys_e) * gate ) ---------------
__global__ __launch_bounds__(256) void k_gemm1(
    const bf16* __restrict__ xb, const bf16* __restrict__ kT,
    const int* __restrict__ assign_token, const float* __restrict__ assign_gate,
    const int* __restrict__ tile_expert, const int* __restrict__ tile_rowstart,
    const int* __restrict__ tile_segend, bf16* __restrict__ h)
{
  __shared__ char smem[BM*BK*2*2];     // A 16KB + B 16KB (bf16)
  __shared__ int   tokens_s[BM];
  __shared__ float gates_s[BM];

  const int tile = blockIdx.x, nb = blockIdx.y;
  const int e = tile_expert[tile];
  if (e < 0) return;
  const int row0 = tile_rowstart[tile];
  const int segend = tile_segend[tile];
  const int tid = threadIdx.x, wave = tid>>6, lane = tid&63;

  if (tid < BM){
    int rg = row0 + tid;
    bool vld = rg < segend;
    tokens_s[tid] = vld ? assign_token[rg] : 0;
    gates_s[tid]  = vld ? assign_gate[rg] : 0.f;
  }
  __syncthreads();

  char* As = smem; char* Bs = smem + BM*BK*2;
  const bf16* gA[4]; const bf16* gB[4]; char* lA[4]; char* lB[4];
#pragma unroll
  for (int i=0;i<4;i++){
    int rl = (wave*4+i)*8 + (lane>>3);
    int c  = (lane&7) ^ (rl&7);                 // source-side XOR pre-swizzle
    gA[i] = xb + (size_t)tokens_s[rl]*DIM + c*8;
    lA[i] = As + (wave*4+i)*1024;
    gB[i] = kT + ((size_t)e*ESZ + nb*BM + rl)*DIM + c*8;
    lB[i] = Bs + (wave*4+i)*1024;
  }

  f32x4 acc[4][4];
#pragma unroll
  for (int m=0;m<4;m++)
#pragma unroll
    for (int n=0;n<4;n++) acc[m][n] = {0.f,0.f,0.f,0.f};

  const int wr0 = (wave>>1)*64, wc0 = (wave&1)*64;

  for (int kt=0; kt<DIM/BK; ++kt){
#pragma unroll
    for (int i=0;i<4;i++){ gload16(gA[i] + kt*BK, lA[i]); gload16(gB[i] + kt*BK, lB[i]); }
    asm volatile("s_waitcnt vmcnt(0)" ::: "memory");
    __syncthreads();
#pragma unroll
    for (int kk=0;kk<2;kk++){
      bf16x8 af[4], bfr[4];
#pragma unroll
      for (int m=0;m<4;m++){
        int row = wr0 + m*16 + (lane&15);
        int kb  = kk*64 + (lane>>4)*16;
        af[m] = *(const bf16x8*)(As + row*128 + (kb ^ ((row&7)<<4)));
      }
#pragma unroll
      for (int n=0;n<4;n++){
        int col = wc0 + n*16 + (lane&15);
        int kb  = kk*64 + (lane>>4)*16;
        bfr[n] = *(const bf16x8*)(Bs + col*128 + (kb ^ ((col&7)<<4)));
      }
#pragma unroll
      for (int m=0;m<4;m++)
#pragma unroll
        for (int n=0;n<4;n++)
          acc[m][n] = __builtin_amdgcn_mfma_f32_16x16x32_bf16(af[m], bfr[n], acc[m][n], 0,0,0);
    }
    __syncthreads();
  }

#pragma unroll
  for (int m=0;m<4;m++)
#pragma unroll
    for (int n=0;n<4;n++){
      int col = wc0 + n*16 + (lane&15);
#pragma unroll
      for (int j=0;j<4;j++){
        int rloc = wr0 + m*16 + ((lane>>4)<<2) + j;
        float v = fmaxf(acc[m][n][j], 0.f) * gates_s[rloc];
        h[(size_t)(row0 + rloc)*ESZ + nb*BM + col] = __float2bfloat16(v);
      }
    }
}

// -------- GEMM2: partial[row] = bf16( h[row] @ values_e )  (no atomics) -----
__global__ __launch_bounds__(256) void k_gemm2(
    const bf16* __restrict__ h, const bf16* __restrict__ vT,
    const int* __restrict__ tile_expert, const int* __restrict__ tile_rowstart,
    bf16* __restrict__ partial)
{
  __shared__ char smem[BM*BK*2*2];

  const int tile = blockIdx.x, nb = blockIdx.y;
  const int e = tile_expert[tile];
  if (e < 0) return;
  const int row0 = tile_rowstart[tile];
  const int tid = threadIdx.x, wave = tid>>6, lane = tid&63;

  char* As = smem; char* Bs = smem + BM*BK*2;
  const bf16* gA[4]; const bf16* gB[4]; char* lA[4]; char* lB[4];
#pragma unroll
  for (int i=0;i<4;i++){
    int rl = (wave*4+i)*8 + (lane>>3);
    int c  = (lane&7) ^ (rl&7);
    gA[i] = h + (size_t)(row0 + rl)*ESZ + c*8;
    lA[i] = As + (wave*4+i)*1024;
    gB[i] = vT + ((size_t)e*DIM + nb*BM + rl)*ESZ + c*8;
    lB[i] = Bs + (wave*4+i)*1024;
  }

  f32x4 acc[4][4];
#pragma unroll
  for (int m=0;m<4;m++)
#pragma unroll
    for (int n=0;n<4;n++) acc[m][n] = {0.f,0.f,0.f,0.f};

  const int wr0 = (wave>>1)*64, wc0 = (wave&1)*64;

  for (int kt=0; kt<ESZ/BK; ++kt){
#pragma unroll
    for (int i=0;i<4;i++){ gload16(gA[i] + kt*BK, lA[i]); gload16(gB[i] + kt*BK, lB[i]); }
    asm volatile("s_waitcnt vmcnt(0)" ::: "memory");
    __syncthreads();
#pragma unroll
    for (int kk=0;kk<2;kk++){
      bf16x8 af[4], bfr[4];
#pragma unroll
      for (int m=0;m<4;m++){
        int row = wr0 + m*16 + (lane&15);
        int kb  = kk*64 + (lane>>4)*16;
        af[m] = *(const bf16x8*)(As + row*128 + (kb ^ ((row&7)<<4)));
      }
#pragma unroll
      for (int n=0;n<4;n++){
        int col = wc0 + n*16 + (lane&15);
        int kb  = kk*64 + (lane>>4)*16;
        bfr[n] = *(const bf16x8*)(Bs + col*128 + (kb ^ ((col&7)<<4)));
      }
#pragma unroll
      for (int m=0;m<4;m++)
#pragma unroll
        for (int n=0;n<4;n++)
          acc[m][n] = __builtin_amdgcn_mfma_f32_16x16x32_bf16(af[m], bfr[n], acc[m][n], 0,0,0);
    }
    __syncthreads();
  }

#pragma unroll
  for (int m=0;m<4;m++)
#pragma unroll
    for (int n=0;n<4;n++){
      int col = wc0 + n*16 + (lane&15);
#pragma unroll
      for (int j=0;j<4;j++){
        int rloc = wr0 + m*16 + ((lane>>4)<<2) + j;
        partial[(size_t)(row0 + rloc)*DIM + nb*BM + col] = __float2bfloat16(acc[m][n][j]);
      }
    }
}

// -------- reduce: out[t] = sum_k partial[inv_rows[t,k]] ---------------------
__global__ __launch_bounds__(256) void k_reduce(const bf16* __restrict__ partial,
    const int* __restrict__ inv_rows, float* __restrict__ out)
{
  const int t = blockIdx.x;
  const int c0 = threadIdx.x * 4;
  int rows[TOPK];
#pragma unroll
  for (int k=0;k<TOPK;k++) rows[k] = inv_rows[t*TOPK+k];
  float a0=0.f,a1=0.f,a2=0.f,a3=0.f;
#pragma unroll
  for (int k=0;k<TOPK;k++){
    ushort4 v = *(const ushort4*)((const unsigned short*)partial + (size_t)rows[k]*DIM + c0);
    a0 += bu2f(v.x); a1 += bu2f(v.y); a2 += bu2f(v.z); a3 += bu2f(v.w);
  }
  float4 o = {a0,a1,a2,a3};
  *(float4*)(out + (size_t)t*DIM + c0) = o;
}

// ---------------------------------------------------------------------------
extern "C" void kernel_launch(void* const* d_in, const int* in_sizes, int n_in,
                              void* d_out, int out_size, void* d_ws, size_t ws_size,
                              hipStream_t stream)
{
  const float* x      = (const float*)d_in[0];
  const float* wg     = (const float*)d_in[1];
  const float* keys   = (const float*)d_in[2];
  const float* values = (const float*)d_in[3];
  float* out = (float*)d_out;

  char* ws = (char*)d_ws;
  size_t off = 0;
  bf16* vT   = (bf16*)(ws+off); off += (size_t)NEXP*DIM*ESZ*2;   // 8 MB
  bf16* hbuf = (bf16*)(ws+off); off += (size_t)MAXROWS*ESZ*2;    // 17.8 MB
  int*   sel_idx      = (int*)  (ws+off); off += (size_t)T_TOK*TOPK*4;
  float* sel_gate     = (float*)(ws+off); off += (size_t)T_TOK*TOPK*4;
  int*   assign_token = (int*)  (ws+off); off += (size_t)MAXROWS*4;
  float* assign_gate  = (float*)(ws+off); off += (size_t)MAXROWS*4;
  int*   inv_rows     = (int*)  (ws+off); off += (size_t)T_TOK*TOPK*4;
  int*   cursors      = (int*)  (ws+off); off += 256;
  int*   tile_expert  = (int*)  (ws+off); off += 4096;
  int*   tile_rowstart= (int*)  (ws+off); off += 4096;
  int*   tile_segend  = (int*)  (ws+off); off += 4096;
  // partial is live only AFTER gemm1; xb/kT are dead after gemm1 -> alias them
  // into partial's tail to cap total workspace at ~98 MB.
  const size_t PARTIAL_BYTES = (size_t)MAXROWS*DIM*2;            // 71.3 MB
  const size_t XB_BYTES = (size_t)T_TOK*DIM*2;                   // 16.8 MB
  const size_t KT_BYTES = (size_t)NEXP*ESZ*DIM*2;                // 8.4 MB
  bf16* partial = (bf16*)(ws+off); off += PARTIAL_BYTES;
  bf16* xb = (bf16*)((char*)partial + PARTIAL_BYTES - XB_BYTES - KT_BYTES);
  bf16* kT = (bf16*)((char*)partial + PARTIAL_BYTES - KT_BYTES);

  k_gate<<<T_TOK/4, 256, 0, stream>>>(x, wg, xb, sel_idx, sel_gate);
  k_transpose<<<dim3(ESZ/32, DIM/32, NEXP), 256, 0, stream>>>(keys, kT, DIM, ESZ);
  k_transpose<<<dim3(DIM/32, ESZ/32, NEXP), 256, 0, stream>>>(values, vT, ESZ, DIM);
  k_meta<<<1, 256, 0, stream>>>(sel_idx, cursors, tile_expert, tile_rowstart, tile_segend);
  k_scatter<<<T_TOK/256, 256, 0, stream>>>(sel_idx, sel_gate, cursors, assign_token,
      assign_gate, inv_rows);
  k_gemm1<<<dim3(MAXTILES, ESZ/BM), 256, 0, stream>>>(xb, kT, assign_token, assign_gate,
      tile_expert, tile_rowstart, tile_segend, hbuf);
  k_gemm2<<<dim3(MAXTILES, DIM/BM), 256, 0, stream>>>(hbuf, vT,
      tile_expert, tile_rowstart, partial);
  k_reduce<<<T_TOK, 256, 0, stream>>>(partial, inv_rows, out);
}

// Round 3
// 161.397 us; speedup vs baseline: 2.1390x; 1.7276x over previous
//
#include <hip/hip_runtime.h>
#include <hip/hip_bf16.h>
#include <stdint.h>

#define T_TOK 8192
#define DIM   1024
#define NEXP  16
#define ESZ   256
#define TOPK  4
#define BM    128
#define BK    64
#define NPAIR (T_TOK*TOPK)                 // 32768
#define NBLK  128                          // hist/scatter blocks (256 pairs each)
#define MAXROWS (T_TOK*TOPK + NEXP*BM)     // 34816 padded assignment rows
#define MAXTILES (T_TOK*TOPK/BM + NEXP)    // 272

typedef __hip_bfloat16 bf16;
typedef short bf16x8 __attribute__((ext_vector_type(8)));
typedef float f32x4 __attribute__((ext_vector_type(4)));

__device__ __forceinline__ unsigned short f2bu(float f){
  __hip_bfloat16 b = __float2bfloat16(f);
  return *reinterpret_cast<unsigned short*>(&b);
}
__device__ __forceinline__ float bu2f(unsigned short u){
  __hip_bfloat16 b = *reinterpret_cast<__hip_bfloat16*>(&u);
  return __bfloat162float(b);
}

__device__ __forceinline__ void gload16(const void* g, void* l){
  __builtin_amdgcn_global_load_lds((const __attribute__((address_space(1))) void*)g,
                                   (__attribute__((address_space(3))) void*)l, 16, 0, 0);
}

// ---------------- gating: logits -> sigmoid -> top4, fused x->bf16 ----------
__global__ __launch_bounds__(256) void k_gate(const float* __restrict__ x,
    const float* __restrict__ wg, bf16* __restrict__ xb,
    int* __restrict__ sel_idx, float* __restrict__ sel_gate)
{
  const int wave = threadIdx.x >> 6, lane = threadIdx.x & 63;
  const int t = blockIdx.x*4 + wave;
  const float* xr = x + (size_t)t*DIM;
  float4 xv[4];
#pragma unroll
  for (int c=0;c<4;c++) xv[c] = *(const float4*)(xr + c*256 + lane*4);
#pragma unroll
  for (int c=0;c<4;c++){
    ushort4 o; o.x=f2bu(xv[c].x); o.y=f2bu(xv[c].y); o.z=f2bu(xv[c].z); o.w=f2bu(xv[c].w);
    *(ushort4*)((unsigned short*)xb + (size_t)t*DIM + c*256 + lane*4) = o;
  }
  float sg[NEXP];
#pragma unroll
  for (int e=0;e<NEXP;e++){
    const float* wr = wg + e*DIM;
    float p = 0.f;
#pragma unroll
    for (int c=0;c<4;c++){
      float4 w = *(const float4*)(wr + c*256 + lane*4);
      p += xv[c].x*w.x + xv[c].y*w.y + xv[c].z*w.z + xv[c].w*w.w;
    }
#pragma unroll
    for (int s=1;s<64;s<<=1) p += __shfl_xor(p, s);
    sg[e] = 1.f/(1.f + expf(-p));
  }
  if (lane==0){
    unsigned chosen = 0;
#pragma unroll
    for (int k=0;k<TOPK;k++){
      float best=-1.f; int bi=0;
#pragma unroll
      for (int e=0;e<NEXP;e++){
        float v = ((chosen>>e)&1u) ? -2.f : sg[e];
        if (v>best){best=v;bi=e;}
      }
      chosen |= 1u<<bi;
      sel_idx[t*TOPK+k]=bi; sel_gate[t*TOPK+k]=best;
    }
  }
}

// ---------------- fp32 [R][C] -> bf16 [C][R] transpose (per expert) ---------
__global__ __launch_bounds__(256) void k_transpose(const float* __restrict__ in,
    bf16* __restrict__ out, int R, int C)
{
  __shared__ float tile[32][33];
  const float* src = in + (size_t)blockIdx.z*R*C;
  bf16* dst = out + (size_t)blockIdx.z*R*C;
  int tx = threadIdx.x & 31, ty = threadIdx.x >> 5;
  int r0 = blockIdx.y*32, c0 = blockIdx.x*32;
#pragma unroll
  for (int i=0;i<4;i++){ int r = ty + i*8; tile[r][tx] = src[(size_t)(r0+r)*C + c0 + tx]; }
  __syncthreads();
#pragma unroll
  for (int i=0;i<4;i++){ int r = ty + i*8; dst[(size_t)(c0+r)*R + r0 + tx] = __float2bfloat16(tile[tx][r]); }
}

// ---------------- per-block histogram (LDS atomics only) --------------------
__global__ __launch_bounds__(256) void k_hist(const int* __restrict__ sel_idx,
    int* __restrict__ block_hist)
{
  __shared__ int h[NEXP];
  if (threadIdx.x < NEXP) h[threadIdx.x]=0;
  __syncthreads();
  atomicAdd(&h[sel_idx[blockIdx.x*256 + threadIdx.x]], 1);
  __syncthreads();
  if (threadIdx.x < NEXP) block_hist[blockIdx.x*NEXP + threadIdx.x] = h[threadIdx.x];
}

// ------- totals -> padded segments + tile map + per-block bases -------------
__global__ void k_meta(const int* __restrict__ block_hist,
    int* __restrict__ tile_expert, int* __restrict__ tile_rowstart,
    int* __restrict__ tile_segend, int* __restrict__ block_base)
{
  __shared__ int cnt[NEXP], seg[NEXP];
  const int tid = threadIdx.x;
  if (tid < NEXP){
    int s=0;
    for (int b=0;b<NBLK;b++) s += block_hist[b*NEXP + tid];
    cnt[tid]=s;
  }
  __syncthreads();
  if (tid==0){
    int off=0, tc=0;
    for (int e=0;e<NEXP;e++){
      seg[e]=off;
      int c = cnt[e];
      int nt = (c + BM - 1)/BM;
      for (int i=0;i<nt;i++){
        tile_expert[tc]=e; tile_rowstart[tc]=off+i*BM; tile_segend[tc]=off+c; tc++;
      }
      off += nt*BM;            // 128-padded segments: tiles never overlap experts
    }
    for (; tc<MAXTILES; tc++) tile_expert[tc]=-1;
  }
  __syncthreads();
  if (tid < NEXP){
    int s = seg[tid];
    for (int b=0;b<NBLK;b++){ block_base[b*NEXP + tid] = s; s += block_hist[b*NEXP + tid]; }
  }
}

// ------- deterministic scatter: ballot rank + wave prefix, no global atomics
__global__ __launch_bounds__(256) void k_scatter(const int* __restrict__ sel_idx,
    const float* __restrict__ sel_gate, const int* __restrict__ block_base,
    int* __restrict__ assign_token, float* __restrict__ assign_gate,
    int* __restrict__ inv_rows)
{
  __shared__ int wcnt[4][NEXP];
  const int p = blockIdx.x*256 + threadIdx.x;
  const int wave = threadIdx.x >> 6, lane = threadIdx.x & 63;
  const int e = sel_idx[p];
  const float g = sel_gate[p];
  int rank = 0;
#pragma unroll
  for (int ee=0; ee<NEXP; ee++){
    unsigned long long m = __ballot(e==ee);
    if (lane==0) wcnt[wave][ee] = (int)__popcll(m);
    if (e==ee) rank = (int)__popcll(m & ((1ull<<lane)-1ull));
  }
  __syncthreads();
  int pre = 0;
  for (int w=0; w<wave; w++) pre += wcnt[w][e];
  const int row = block_base[blockIdx.x*NEXP + e] + pre + rank;
  assign_token[row] = p >> 2;
  assign_gate[row]  = g;
  inv_rows[p] = row;
}

// ---------------- GEMM1: h = bf16( relu(Xg @ keys_e) * gate ) ---------------
__global__ __launch_bounds__(256) void k_gemm1(
    const bf16* __restrict__ xb, const bf16* __restrict__ kT,
    const int* __restrict__ assign_token, const float* __restrict__ assign_gate,
    const int* __restrict__ tile_expert, const int* __restrict__ tile_rowstart,
    const int* __restrict__ tile_segend, bf16* __restrict__ h)
{
  __shared__ char smem[BM*BK*2*2];     // A 16KB + B 16KB (bf16)
  __shared__ int   tokens_s[BM];
  __shared__ float gates_s[BM];

  const int tile = blockIdx.x, nb = blockIdx.y;
  const int e = tile_expert[tile];
  if (e < 0) return;
  const int row0 = tile_rowstart[tile];
  const int segend = tile_segend[tile];
  const int tid = threadIdx.x, wave = tid>>6, lane = tid&63;

  if (tid < BM){
    int rg = row0 + tid;
    bool vld = rg < segend;
    tokens_s[tid] = vld ? assign_token[rg] : 0;
    gates_s[tid]  = vld ? assign_gate[rg] : 0.f;
  }
  __syncthreads();

  char* As = smem; char* Bs = smem + BM*BK*2;
  const bf16* gA[4]; const bf16* gB[4]; char* lA[4]; char* lB[4];
#pragma unroll
  for (int i=0;i<4;i++){
    int rl = (wave*4+i)*8 + (lane>>3);
    int c  = (lane&7) ^ (rl&7);                 // source-side XOR pre-swizzle
    gA[i] = xb + (size_t)tokens_s[rl]*DIM + c*8;
    lA[i] = As + (wave*4+i)*1024;
    gB[i] = kT + ((size_t)e*ESZ + nb*BM + rl)*DIM + c*8;
    lB[i] = Bs + (wave*4+i)*1024;
  }

  f32x4 acc[4][4];
#pragma unroll
  for (int m=0;m<4;m++)
#pragma unroll
    for (int n=0;n<4;n++) acc[m][n] = {0.f,0.f,0.f,0.f};

  const int wr0 = (wave>>1)*64, wc0 = (wave&1)*64;

  for (int kt=0; kt<DIM/BK; ++kt){
#pragma unroll
    for (int i=0;i<4;i++){ gload16(gA[i] + kt*BK, lA[i]); gload16(gB[i] + kt*BK, lB[i]); }
    asm volatile("s_waitcnt vmcnt(0)" ::: "memory");
    __syncthreads();
#pragma unroll
    for (int kk=0;kk<2;kk++){
      bf16x8 af[4], bfr[4];
#pragma unroll
      for (int m=0;m<4;m++){
        int row = wr0 + m*16 + (lane&15);
        int kb  = kk*64 + (lane>>4)*16;
        af[m] = *(const bf16x8*)(As + row*128 + (kb ^ ((row&7)<<4)));
      }
#pragma unroll
      for (int n=0;n<4;n++){
        int col = wc0 + n*16 + (lane&15);
        int kb  = kk*64 + (lane>>4)*16;
        bfr[n] = *(const bf16x8*)(Bs + col*128 + (kb ^ ((col&7)<<4)));
      }
#pragma unroll
      for (int m=0;m<4;m++)
#pragma unroll
        for (int n=0;n<4;n++)
          acc[m][n] = __builtin_amdgcn_mfma_f32_16x16x32_bf16(af[m], bfr[n], acc[m][n], 0,0,0);
    }
    __syncthreads();
  }

#pragma unroll
  for (int m=0;m<4;m++)
#pragma unroll
    for (int n=0;n<4;n++){
      int col = wc0 + n*16 + (lane&15);
#pragma unroll
      for (int j=0;j<4;j++){
        int rloc = wr0 + m*16 + ((lane>>4)<<2) + j;
        float v = fmaxf(acc[m][n][j], 0.f) * gates_s[rloc];
        h[(size_t)(row0 + rloc)*ESZ + nb*BM + col] = __float2bfloat16(v);
      }
    }
}

// -------- GEMM2: partial[row] = bf16( h[row] @ values_e )  (no atomics) -----
__global__ __launch_bounds__(256) void k_gemm2(
    const bf16* __restrict__ h, const bf16* __restrict__ vT,
    const int* __restrict__ tile_expert, const int* __restrict__ tile_rowstart,
    bf16* __restrict__ partial)
{
  __shared__ char smem[BM*BK*2*2];

  const int tile = blockIdx.x, nb = blockIdx.y;
  const int e = tile_expert[tile];
  if (e < 0) return;
  const int row0 = tile_rowstart[tile];
  const int tid = threadIdx.x, wave = tid>>6, lane = tid&63;

  char* As = smem; char* Bs = smem + BM*BK*2;
  const bf16* gA[4]; const bf16* gB[4]; char* lA[4]; char* lB[4];
#pragma unroll
  for (int i=0;i<4;i++){
    int rl = (wave*4+i)*8 + (lane>>3);
    int c  = (lane&7) ^ (rl&7);
    gA[i] = h + (size_t)(row0 + rl)*ESZ + c*8;
    lA[i] = As + (wave*4+i)*1024;
    gB[i] = vT + ((size_t)e*DIM + nb*BM + rl)*ESZ + c*8;
    lB[i] = Bs + (wave*4+i)*1024;
  }

  f32x4 acc[4][4];
#pragma unroll
  for (int m=0;m<4;m++)
#pragma unroll
    for (int n=0;n<4;n++) acc[m][n] = {0.f,0.f,0.f,0.f};

  const int wr0 = (wave>>1)*64, wc0 = (wave&1)*64;

  for (int kt=0; kt<ESZ/BK; ++kt){
#pragma unroll
    for (int i=0;i<4;i++){ gload16(gA[i] + kt*BK, lA[i]); gload16(gB[i] + kt*BK, lB[i]); }
    asm volatile("s_waitcnt vmcnt(0)" ::: "memory");
    __syncthreads();
#pragma unroll
    for (int kk=0;kk<2;kk++){
      bf16x8 af[4], bfr[4];
#pragma unroll
      for (int m=0;m<4;m++){
        int row = wr0 + m*16 + (lane&15);
        int kb  = kk*64 + (lane>>4)*16;
        af[m] = *(const bf16x8*)(As + row*128 + (kb ^ ((row&7)<<4)));
      }
#pragma unroll
      for (int n=0;n<4;n++){
        int col = wc0 + n*16 + (lane&15);
        int kb  = kk*64 + (lane>>4)*16;
        bfr[n] = *(const bf16x8*)(Bs + col*128 + (kb ^ ((col&7)<<4)));
      }
#pragma unroll
      for (int m=0;m<4;m++)
#pragma unroll
        for (int n=0;n<4;n++)
          acc[m][n] = __builtin_amdgcn_mfma_f32_16x16x32_bf16(af[m], bfr[n], acc[m][n], 0,0,0);
    }
    __syncthreads();
  }

#pragma unroll
  for (int m=0;m<4;m++)
#pragma unroll
    for (int n=0;n<4;n++){
      int col = wc0 + n*16 + (lane&15);
#pragma unroll
      for (int j=0;j<4;j++){
        int rloc = wr0 + m*16 + ((lane>>4)<<2) + j;
        partial[(size_t)(row0 + rloc)*DIM + nb*BM + col] = __float2bfloat16(acc[m][n][j]);
      }
    }
}

// -------- reduce: out[t] = sum_k partial[inv_rows[t,k]] ---------------------
__global__ __launch_bounds__(256) void k_reduce(const bf16* __restrict__ partial,
    const int* __restrict__ inv_rows, float* __restrict__ out)
{
  const int t = blockIdx.x;
  const int c0 = threadIdx.x * 4;
  int rows[TOPK];
#pragma unroll
  for (int k=0;k<TOPK;k++) rows[k] = inv_rows[t*TOPK+k];
  float a0=0.f,a1=0.f,a2=0.f,a3=0.f;
#pragma unroll
  for (int k=0;k<TOPK;k++){
    ushort4 v = *(const ushort4*)((const unsigned short*)partial + (size_t)rows[k]*DIM + c0);
    a0 += bu2f(v.x); a1 += bu2f(v.y); a2 += bu2f(v.z); a3 += bu2f(v.w);
  }
  float4 o = {a0,a1,a2,a3};
  *(float4*)(out + (size_t)t*DIM + c0) = o;
}

// ---------------------------------------------------------------------------
extern "C" void kernel_launch(void* const* d_in, const int* in_sizes, int n_in,
                              void* d_out, int out_size, void* d_ws, size_t ws_size,
                              hipStream_t stream)
{
  const float* x      = (const float*)d_in[0];
  const float* wg     = (const float*)d_in[1];
  const float* keys   = (const float*)d_in[2];
  const float* values = (const float*)d_in[3];
  float* out = (float*)d_out;

  char* ws = (char*)d_ws;
  size_t off = 0;
  bf16* vT   = (bf16*)(ws+off); off += (size_t)NEXP*DIM*ESZ*2;   // 8 MB
  bf16* hbuf = (bf16*)(ws+off); off += (size_t)MAXROWS*ESZ*2;    // 17.8 MB
  int*   sel_idx      = (int*)  (ws+off); off += (size_t)NPAIR*4;
  float* sel_gate     = (float*)(ws+off); off += (size_t)NPAIR*4;
  int*   assign_token = (int*)  (ws+off); off += (size_t)MAXROWS*4;
  float* assign_gate  = (float*)(ws+off); off += (size_t)MAXROWS*4;
  int*   inv_rows     = (int*)  (ws+off); off += (size_t)NPAIR*4;
  int*   block_hist   = (int*)  (ws+off); off += (size_t)NBLK*NEXP*4;
  int*   block_base   = (int*)  (ws+off); off += (size_t)NBLK*NEXP*4;
  int*   tile_expert  = (int*)  (ws+off); off += 4096;
  int*   tile_rowstart= (int*)  (ws+off); off += 4096;
  int*   tile_segend  = (int*)  (ws+off); off += 4096;
  // partial is live only AFTER gemm1; xb/kT are dead after gemm1 -> alias them
  // into partial's tail to cap total workspace at ~98 MB.
  const size_t PARTIAL_BYTES = (size_t)MAXROWS*DIM*2;            // 71.3 MB
  const size_t XB_BYTES = (size_t)T_TOK*DIM*2;                   // 16.8 MB
  const size_t KT_BYTES = (size_t)NEXP*ESZ*DIM*2;                // 8.4 MB
  bf16* partial = (bf16*)(ws+off); off += PARTIAL_BYTES;
  bf16* xb = (bf16*)((char*)partial + PARTIAL_BYTES - XB_BYTES - KT_BYTES);
  bf16* kT = (bf16*)((char*)partial + PARTIAL_BYTES - KT_BYTES);

  k_gate<<<T_TOK/4, 256, 0, stream>>>(x, wg, xb, sel_idx, sel_gate);
  k_transpose<<<dim3(ESZ/32, DIM/32, NEXP), 256, 0, stream>>>(keys, kT, DIM, ESZ);
  k_transpose<<<dim3(DIM/32, ESZ/32, NEXP), 256, 0, stream>>>(values, vT, ESZ, DIM);
  k_hist<<<NBLK, 256, 0, stream>>>(sel_idx, block_hist);
  k_meta<<<1, 256, 0, stream>>>(block_hist, tile_expert, tile_rowstart, tile_segend, block_base);
  k_scatter<<<NBLK, 256, 0, stream>>>(sel_idx, sel_gate, block_base, assign_token,
      assign_gate, inv_rows);
  k_gemm1<<<dim3(MAXTILES, ESZ/BM), 256, 0, stream>>>(xb, kT, assign_token, assign_gate,
      tile_expert, tile_rowstart, tile_segend, hbuf);
  k_gemm2<<<dim3(MAXTILES, DIM/BM), 256, 0, stream>>>(hbuf, vT,
      tile_expert, tile_rowstart, partial);
  k_reduce<<<T_TOK, 256, 0, stream>>>(partial, inv_rows, out);
}